// Round 6
// baseline (333.077 us; speedup 1.0000x reference)
//
#include <hip/hip_runtime.h>

// ModConv2D — StyleGAN2 modulated conv as implicit GEMM, f16 MFMA.
// B=16, H=W=64, CIN=COUT=256, 3x3 SAME, fp32 I/O.
//
// R6 structure: B-fragments load DIRECTLY from global (Wt[co][k] f16 is the
// exact MFMA B layout; 1.18 MB -> L2-resident). LDS holds only the modulated
// x-window (4x66x32ci f16), double-buffered -> ONE barrier per ci-slice,
// 144 MFMAs between barriers, LDS traffic halved vs R5.

#define HH 64
#define WW 64
#define CI 256
#define CO 256
#define KTOT 2304
#define CIPITCH 40        // ushorts per (row,col): 32 ci + 8 pad (80 B)
#define XCOLS 66
#define XSSZ (4 * XCOLS * CIPITCH)   // 10560 ushorts per buffer

typedef float    f32x4 __attribute__((ext_vector_type(4)));
typedef _Float16 f16x8 __attribute__((ext_vector_type(8)));
typedef __fp16   fp16x2 __attribute__((ext_vector_type(2)));

__device__ __forceinline__ unsigned pk2(float a, float b) {
    fp16x2 h = __builtin_amdgcn_cvt_pkrtz(a, b);
    return __builtin_bit_cast(unsigned, h);
}

// ---- demod scale[b][co] = rsqrt(sum_{t,ci} (kern*(style+1))^2 + 1e-8) ----
__global__ __launch_bounds__(1024) void modscale_kernel(
    const float* __restrict__ kern,    // [9][CI][CO]
    const float* __restrict__ style,   // [B][CI]
    float* __restrict__ scale)         // [B][CO] final rsqrt factor
{
    const int b   = blockIdx.x;
    const int tid = threadIdx.x;
    const int co  = tid & 255;
    const int q   = tid >> 8;

    __shared__ float s_style[CI];
    __shared__ float s_part[1024];

    if (tid < CI) s_style[tid] = style[b * CI + tid] + 1.0f;
    __syncthreads();

    float acc = 0.f;
    for (int t = 0; t < 9; ++t) {
        const float* kp = kern + (size_t)t * CI * CO + co;
        #pragma unroll 4
        for (int ci = q * 64; ci < q * 64 + 64; ++ci) {
            float m = kp[ci * CO] * s_style[ci];
            acc += m * m;
        }
    }
    s_part[tid] = acc;
    __syncthreads();
    if (q == 0) {
        float s = s_part[co] + s_part[256 + co] + s_part[512 + co] + s_part[768 + co];
        scale[b * CO + co] = 1.0f / sqrtf(s + 1e-8f);
    }
}

// ---- transpose + f16-convert weights: Wt[co][k] ----
__global__ __launch_bounds__(256) void prep_wt(const float* __restrict__ kern,
                                               ushort* __restrict__ Wt) {
    __shared__ ushort tile[64][65];
    const int kt = blockIdx.x >> 2;
    const int ct = blockIdx.x & 3;
    const int k0 = kt * 64, c0 = ct * 64;
    const int tid = threadIdx.x;
    const int r = tid >> 2, q = tid & 3;

    const float* src = kern + (size_t)(k0 + r) * CO + c0 + q * 16;
    #pragma unroll
    for (int j = 0; j < 16; ++j) {
        _Float16 h = (_Float16)src[j];
        tile[q * 16 + j][r] = __builtin_bit_cast(unsigned short, h);
    }
    __syncthreads();
    ushort* dst = Wt + (size_t)(c0 + r) * KTOT + k0 + q * 16;
    #pragma unroll
    for (int j = 0; j < 16; ++j) dst[j] = tile[r][q * 16 + j];
}

// ---- implicit-GEMM conv ----
__global__ __launch_bounds__(256) void gemm_conv(
    const float* __restrict__ x,        // [B][H][W][CI] fp32
    const ushort* __restrict__ Wt,      // [CO][KTOT] f16 (MFMA B layout)
    const float* __restrict__ style,    // [B][CI]
    const float* __restrict__ scale,    // [B][CO] rsqrt demod factor
    float* __restrict__ y)              // [B][H][W][CO] fp32
{
    __shared__ __align__(16) ushort xs[2 * XSSZ];   // 42240 B double-buffered
    __shared__ float s_style[CI];

    const int tid  = threadIdx.x;
    const int lane = tid & 63;
    const int wave = tid >> 6;

    const int mtile = blockIdx.x >> 1;
    const int n0    = (blockIdx.x & 1) * 128;
    const int p0    = mtile * 128;            // 2 image rows of one sample
    const int b     = p0 >> 12;
    const int h0    = (p0 >> 6) & 63;

    s_style[tid] = style[b * CI + tid] + 1.0f;

    const int wm = (wave & 1) * 64;
    const int wn = (wave >> 1) * 64;
    const int fr = lane & 15;
    const int fq = lane >> 4;
    const int wrow  = wm >> 6;                 // 0 or 1
    const int xlane = fr * CIPITCH + fq * 8;
    const ushort* wbase = Wt + (size_t)(n0 + wn + fr) * KTOT + fq * 8;

    // stage modulated f16 x-window for ci-slice c into buffer buf
    auto stage = [&](int c, int buf) {
        ushort* dst = xs + buf * XSSZ;
        #pragma unroll
        for (int p = 0; p < 9; ++p) {
            const int task = p * 256 + tid;
            if (task < 2112) {
                const int rowcol = task >> 3;
                const int chunk  = task & 7;
                const int row = rowcol / XCOLS;
                const int col = rowcol - row * XCOLS;
                const int rg = h0 - 1 + row;
                const int cg = col - 1;
                f32x4 v = {0.f, 0.f, 0.f, 0.f};
                if ((unsigned)rg < 64u && (unsigned)cg < 64u)
                    v = *(const f32x4*)(x + ((size_t)((b * HH + rg) * WW + cg)) * CI
                                          + c * 32 + chunk * 4);
                const f32x4 st = *(const f32x4*)(s_style + c * 32 + chunk * 4);
                const f32x4 m = v * st;
                uint2 u;
                u.x = pk2(m.x, m.y);
                u.y = pk2(m.z, m.w);
                *(uint2*)(dst + rowcol * CIPITCH + chunk * 4) = u;
            }
        }
    };

    f32x4 acc[4][4] = {};

    __syncthreads();          // s_style visible
    stage(0, 0);

    for (int c = 0; c < 8; ++c) {
        __syncthreads();      // buf c&1 visible; readers of buf (c+1)&1 done
        if (c < 7) stage(c + 1, (c + 1) & 1);   // loads overlap MFMAs below

        const ushort* xb = xs + (c & 1) * XSSZ;
        const ushort* wb = wbase + c * 32;

        #pragma unroll
        for (int t = 0; t < 9; ++t) {
            const int dh = t / 3;
            const int dw = t - dh * 3;
            f16x8 af[4], bf[4];
            const ushort* ab = xb + ((wrow + dh) * XCOLS + dw) * CIPITCH + xlane;
            #pragma unroll
            for (int i = 0; i < 4; ++i)
                af[i] = *(const f16x8*)(ab + i * 16 * CIPITCH);
            #pragma unroll
            for (int j = 0; j < 4; ++j)
                bf[j] = *(const f16x8*)(wb + (size_t)j * 16 * KTOT + t * 256);
            #pragma unroll
            for (int i = 0; i < 4; ++i)
                #pragma unroll
                for (int j = 0; j < 4; ++j)
                    acc[i][j] = __builtin_amdgcn_mfma_f32_16x16x32_f16(
                        af[i], bf[j], acc[i][j], 0, 0, 0);
        }
    }

    // ---- epilogue: D col=lane&15, row=(lane>>4)*4+reg ----
    float sc[4];
    #pragma unroll
    for (int j = 0; j < 4; ++j)
        sc[j] = scale[b * CO + n0 + wn + j * 16 + fr];
    #pragma unroll
    for (int i = 0; i < 4; ++i) {
        const int m_base = p0 + wm + i * 16 + fq * 4;
        #pragma unroll
        for (int j = 0; j < 4; ++j) {
            float* yp = y + (size_t)m_base * CO + n0 + wn + j * 16 + fr;
            #pragma unroll
            for (int r = 0; r < 4; ++r)
                yp[(size_t)r * CO] = acc[i][j][r] * sc[j];
        }
    }
}

extern "C" void kernel_launch(void* const* d_in, const int* in_sizes, int n_in,
                              void* d_out, int out_size, void* d_ws, size_t ws_size,
                              hipStream_t stream) {
    const float* x     = (const float*)d_in[0];  // [16,64,64,256]
    const float* style = (const float*)d_in[1];  // [16,256]
    const float* kern  = (const float*)d_in[2];  // [3,3,256,256]
    float* out = (float*)d_out;                  // [16,64,64,256]

    float*  scale = (float*)d_ws;                        // 16*256 fp32
    ushort* Wt    = (ushort*)((char*)d_ws + 16384);      // [256][2304] f16

    modscale_kernel<<<16, 1024, 0, stream>>>(kern, style, scale);
    prep_wt<<<144, 256, 0, stream>>>(kern, Wt);
    gemm_conv<<<512 * 2, 256, 0, stream>>>(x, Wt, style, scale, out);
}